// Round 4
// baseline (122.408 us; speedup 1.0000x reference)
//
#include <hip/hip_runtime.h>

// 3x3 conv, stride 1, pad 1, 4096x4096 fp32. Each thread: 4x4 output tile.
// Halo columns via __shfl (intra-wave) + LDS (inter-wave) + 2 single-lane
// global loads per block (block boundary). Hot VMEM is 16 B/lane only:
// 6 dwordx4 loads + 4 dwordx4 stores per thread (was 22 VMEM insts/wave).

#define H 4096
#define W 4096
#define COLS_PER_THREAD 4
#define ROWS_PER_THREAD 4
#define BLOCK 256
#define NWAVES (BLOCK / 64)

__global__ __launch_bounds__(BLOCK) void conv3x3_kernel(
    const float* __restrict__ x, const float* __restrict__ w9,
    const float* __restrict__ bias, float* __restrict__ out) {
    const int tid = threadIdx.x;
    const int wave = tid >> 6;
    const int lane = tid & 63;
    const int c = (blockIdx.x * BLOCK + tid) * COLS_PER_THREAD;
    const int r0 = blockIdx.y * ROWS_PER_THREAD;

    float wv[9];
#pragma unroll
    for (int i = 0; i < 9; ++i) wv[i] = w9[i];
    const float b = bias[0];

    // Load the 6 contributing input rows (aligned float4 only).
    float4 v[6];
#pragma unroll
    for (int i = 0; i < 6; ++i) {
        const int rr = r0 + i - 1;
        if (rr >= 0 && rr < H) {
            v[i] = *(const float4*)(x + (size_t)rr * W + c);
        } else {
            v[i] = make_float4(0.f, 0.f, 0.f, 0.f);
        }
    }

    // Inter-wave halo exchange via LDS (block-interior wave boundaries).
    __shared__ float sL[6][NWAVES];  // lane 0's v.x per wave/row
    __shared__ float sR[6][NWAVES];  // lane 63's v.w per wave/row
    if (lane == 0) {
#pragma unroll
        for (int i = 0; i < 6; ++i) sL[i][wave] = v[i].x;
    }
    if (lane == 63) {
#pragma unroll
        for (int i = 0; i < 6; ++i) sR[i][wave] = v[i].w;
    }

    // Block-boundary halo: single-lane global loads (waves 1-2 skip via execz).
    float gl6[6] = {0, 0, 0, 0, 0, 0};
    float gr6[6] = {0, 0, 0, 0, 0, 0};
    if (tid == 0 && blockIdx.x > 0) {
#pragma unroll
        for (int i = 0; i < 6; ++i) {
            const int rr = r0 + i - 1;
            if (rr >= 0 && rr < H) gl6[i] = x[(size_t)rr * W + c - 1];
        }
    }
    if (tid == BLOCK - 1 && c + COLS_PER_THREAD < W) {
#pragma unroll
        for (int i = 0; i < 6; ++i) {
            const int rr = r0 + i - 1;
            if (rr >= 0 && rr < H) gr6[i] = x[(size_t)rr * W + c + 4];
        }
    }
    __syncthreads();

    // Resolve left/right neighbor columns per input row.
    float lf[6], rt[6];
#pragma unroll
    for (int i = 0; i < 6; ++i) {
        float ln = __shfl_up(v[i].w, 1);
        if (lane == 0) ln = (wave > 0) ? sR[i][wave - 1] : gl6[i];
        float rn = __shfl_down(v[i].x, 1);
        if (lane == 63) rn = (wave < NWAVES - 1) ? sL[i][wave + 1] : gr6[i];
        lf[i] = ln;
        rt[i] = rn;
    }

    float4 acc[ROWS_PER_THREAD];
#pragma unroll
    for (int j = 0; j < ROWS_PER_THREAD; ++j) acc[j] = make_float4(b, b, b, b);

#pragma unroll
    for (int j = 0; j < ROWS_PER_THREAD; ++j) {
#pragma unroll
        for (int dr = 0; dr < 3; ++dr) {
            const int i = j + dr;
            const float w0 = wv[dr * 3 + 0];
            const float w1 = wv[dr * 3 + 1];
            const float w2 = wv[dr * 3 + 2];
            acc[j].x = fmaf(w0, lf[i],  fmaf(w1, v[i].x, fmaf(w2, v[i].y, acc[j].x)));
            acc[j].y = fmaf(w0, v[i].x, fmaf(w1, v[i].y, fmaf(w2, v[i].z, acc[j].y)));
            acc[j].z = fmaf(w0, v[i].y, fmaf(w1, v[i].z, fmaf(w2, v[i].w, acc[j].z)));
            acc[j].w = fmaf(w0, v[i].z, fmaf(w1, v[i].w, fmaf(w2, rt[i],  acc[j].w)));
        }
    }

#pragma unroll
    for (int j = 0; j < ROWS_PER_THREAD; ++j) {
        *(float4*)(out + (size_t)(r0 + j) * W + c) = acc[j];
    }
}

extern "C" void kernel_launch(void* const* d_in, const int* in_sizes, int n_in,
                              void* d_out, int out_size, void* d_ws, size_t ws_size,
                              hipStream_t stream) {
    const float* x = (const float*)d_in[0];
    const float* w = (const float*)d_in[1];
    const float* bias = (const float*)d_in[2];
    float* out = (float*)d_out;

    dim3 block(BLOCK, 1, 1);
    dim3 grid(W / (BLOCK * COLS_PER_THREAD), H / ROWS_PER_THREAD, 1);
    conv3x3_kernel<<<grid, block, 0, stream>>>(x, w, bias, out);
}

// Round 6
// 113.781 us; speedup vs baseline: 1.0758x; 1.0758x over previous
//
#include <hip/hip_runtime.h>

// 3x3 conv, stride 1, pad 1, 4096x4096 fp32.
// Block = 256 threads covering a 1024-col x 16-row stripe, walked in 4 steps
// of 4 output rows. The 2 overlapping input rows between steps rotate in
// registers (demand reads 1.5x -> ~1.17x); next-step loads issue before the
// current step's FMAs (software pipeline). Output uses nontemporal stores so
// the write stream doesn't evict cached input rows from L2.

#define H 4096
#define W 4096
#define CPT 4      // cols per thread
#define RPT 4      // rows per step
#define STEPS 4    // steps per block (stripe = 16 rows)
#define BLOCK 256

typedef float vfloat4 __attribute__((ext_vector_type(4)));

__global__ __launch_bounds__(BLOCK) void conv3x3_stripe(
    const float* __restrict__ x, const float* __restrict__ w9,
    const float* __restrict__ bias, float* __restrict__ out) {
    const int c = (blockIdx.x * BLOCK + threadIdx.x) * CPT;
    const int rbase = blockIdx.y * (STEPS * RPT);

    float wv[9];
#pragma unroll
    for (int i = 0; i < 9; ++i) wv[i] = w9[i];
    const float b = bias[0];

    vfloat4 v[6];
    float lf[6], rt[6];

    // Initial 6 input rows: rbase-1 .. rbase+4.
#pragma unroll
    for (int i = 0; i < 6; ++i) {
        const int rr = rbase - 1 + i;
        if (rr >= 0 && rr < H) {
            const float* row = x + (size_t)rr * W + c;
            v[i] = *(const vfloat4*)row;
            lf[i] = (c > 0) ? row[-1] : 0.0f;
            rt[i] = (c + CPT < W) ? row[CPT] : 0.0f;
        } else {
            v[i] = (vfloat4)(0.f);
            lf[i] = 0.f;
            rt[i] = 0.f;
        }
    }

#pragma unroll
    for (int s = 0; s < STEPS; ++s) {
        const int r0 = rbase + s * RPT;

        // Prefetch the next step's 4 new rows (r0+5 .. r0+8) BEFORE compute.
        vfloat4 nv[4];
        float nlf[4], nrt[4];
        if (s < STEPS - 1) {
#pragma unroll
            for (int k = 0; k < 4; ++k) {
                const int rr = r0 + 5 + k;
                if (rr < H) {
                    const float* row = x + (size_t)rr * W + c;
                    nv[k] = *(const vfloat4*)row;
                    nlf[k] = (c > 0) ? row[-1] : 0.0f;
                    nrt[k] = (c + CPT < W) ? row[CPT] : 0.0f;
                } else {
                    nv[k] = (vfloat4)(0.f);
                    nlf[k] = 0.f;
                    nrt[k] = 0.f;
                }
            }
        }

        vfloat4 acc[RPT];
#pragma unroll
        for (int j = 0; j < RPT; ++j) acc[j] = (vfloat4)(b);

#pragma unroll
        for (int j = 0; j < RPT; ++j) {
#pragma unroll
            for (int dr = 0; dr < 3; ++dr) {
                const int i = j + dr;
                const float w0 = wv[dr * 3 + 0];
                const float w1 = wv[dr * 3 + 1];
                const float w2 = wv[dr * 3 + 2];
                acc[j].x = fmaf(w0, lf[i],  fmaf(w1, v[i].x, fmaf(w2, v[i].y, acc[j].x)));
                acc[j].y = fmaf(w0, v[i].x, fmaf(w1, v[i].y, fmaf(w2, v[i].z, acc[j].y)));
                acc[j].z = fmaf(w0, v[i].y, fmaf(w1, v[i].z, fmaf(w2, v[i].w, acc[j].z)));
                acc[j].w = fmaf(w0, v[i].z, fmaf(w1, v[i].w, fmaf(w2, rt[i],  acc[j].w)));
            }
        }

#pragma unroll
        for (int j = 0; j < RPT; ++j) {
            __builtin_nontemporal_store(acc[j],
                (vfloat4*)(out + (size_t)(r0 + j) * W + c));
        }

        // Rotate: keep rows r0+3, r0+4; bring in the prefetched 4.
        if (s < STEPS - 1) {
            v[0] = v[4];  v[1] = v[5];
            lf[0] = lf[4]; lf[1] = lf[5];
            rt[0] = rt[4]; rt[1] = rt[5];
#pragma unroll
            for (int k = 0; k < 4; ++k) {
                v[2 + k] = nv[k];
                lf[2 + k] = nlf[k];
                rt[2 + k] = nrt[k];
            }
        }
    }
}

extern "C" void kernel_launch(void* const* d_in, const int* in_sizes, int n_in,
                              void* d_out, int out_size, void* d_ws, size_t ws_size,
                              hipStream_t stream) {
    const float* x = (const float*)d_in[0];
    const float* w = (const float*)d_in[1];
    const float* bias = (const float*)d_in[2];
    float* out = (float*)d_out;

    dim3 block(BLOCK, 1, 1);
    dim3 grid(W / (BLOCK * CPT), H / (STEPS * RPT), 1);
    conv3x3_stripe<<<grid, block, 0, stream>>>(x, w, bias, out);
}

// Round 7
// 112.270 us; speedup vs baseline: 1.0903x; 1.0135x over previous
//
#include <hip/hip_runtime.h>

// 3x3 conv, stride 1, pad 1, 4096x4096 fp32.
// Block = 256 threads covering a 1024-col x 16-row stripe, walked in 4 steps
// of 4 output rows. Register rotation for the 2 overlapping rows; NT stores.
// R7 change: prefetch DISTANCE 2 — rows for step s+2 are issued during step
// s, doubling bytes in flight per thread to cover HBM latency (~900 cyc).

#define H 4096
#define W 4096
#define CPT 4      // cols per thread
#define RPT 4      // rows per step
#define STEPS 4    // steps per block (stripe = 16 rows)
#define BLOCK 256

typedef float vfloat4 __attribute__((ext_vector_type(4)));

__device__ __forceinline__ void load_row(const float* __restrict__ x, int rr,
                                         int c, vfloat4& v, float& lf, float& rt) {
    if (rr >= 0 && rr < H) {
        const float* row = x + (size_t)rr * W + c;
        v = *(const vfloat4*)row;
        lf = (c > 0) ? row[-1] : 0.0f;
        rt = (c + CPT < W) ? row[CPT] : 0.0f;
    } else {
        v = (vfloat4)(0.f);
        lf = 0.f;
        rt = 0.f;
    }
}

__global__ __launch_bounds__(BLOCK, 4) void conv3x3_stripe(
    const float* __restrict__ x, const float* __restrict__ w9,
    const float* __restrict__ bias, float* __restrict__ out) {
    const int c = (blockIdx.x * BLOCK + threadIdx.x) * CPT;
    const int rbase = blockIdx.y * (STEPS * RPT);

    float wv[9];
#pragma unroll
    for (int i = 0; i < 9; ++i) wv[i] = w9[i];
    const float b = bias[0];

    // Current window: rows rbase-1 .. rbase+4.
    vfloat4 v[6];
    float lf[6], rt[6];
#pragma unroll
    for (int i = 0; i < 6; ++i) load_row(x, rbase - 1 + i, c, v[i], lf[i], rt[i]);

    // Prefetch stage 1: rows rbase+5 .. rbase+8 (for step 1).
    vfloat4 p[4];
    float plf[4], prt[4];
#pragma unroll
    for (int k = 0; k < 4; ++k) load_row(x, rbase + 5 + k, c, p[k], plf[k], prt[k]);

#pragma unroll
    for (int s = 0; s < STEPS; ++s) {
        const int r0 = rbase + s * RPT;

        // Prefetch stage 2: rows r0+9 .. r0+12 (for step s+2).
        vfloat4 q[4];
        float qlf[4], qrt[4];
        if (s < STEPS - 2) {
#pragma unroll
            for (int k = 0; k < 4; ++k)
                load_row(x, r0 + 9 + k, c, q[k], qlf[k], qrt[k]);
        }

        vfloat4 acc[RPT];
#pragma unroll
        for (int j = 0; j < RPT; ++j) acc[j] = (vfloat4)(b);

#pragma unroll
        for (int j = 0; j < RPT; ++j) {
#pragma unroll
            for (int dr = 0; dr < 3; ++dr) {
                const int i = j + dr;
                const float w0 = wv[dr * 3 + 0];
                const float w1 = wv[dr * 3 + 1];
                const float w2 = wv[dr * 3 + 2];
                acc[j].x = fmaf(w0, lf[i],  fmaf(w1, v[i].x, fmaf(w2, v[i].y, acc[j].x)));
                acc[j].y = fmaf(w0, v[i].x, fmaf(w1, v[i].y, fmaf(w2, v[i].z, acc[j].y)));
                acc[j].z = fmaf(w0, v[i].y, fmaf(w1, v[i].z, fmaf(w2, v[i].w, acc[j].z)));
                acc[j].w = fmaf(w0, v[i].z, fmaf(w1, v[i].w, fmaf(w2, rt[i],  acc[j].w)));
            }
        }

#pragma unroll
        for (int j = 0; j < RPT; ++j) {
            __builtin_nontemporal_store(acc[j],
                (vfloat4*)(out + (size_t)(r0 + j) * W + c));
        }

        // Rotate window and pipeline stages (full unroll -> pure renaming).
        if (s < STEPS - 1) {
            v[0] = v[4];  v[1] = v[5];
            lf[0] = lf[4]; lf[1] = lf[5];
            rt[0] = rt[4]; rt[1] = rt[5];
#pragma unroll
            for (int k = 0; k < 4; ++k) {
                v[2 + k] = p[k];
                lf[2 + k] = plf[k];
                rt[2 + k] = prt[k];
                p[k] = q[k];
                plf[k] = qlf[k];
                prt[k] = qrt[k];
            }
        }
    }
}

extern "C" void kernel_launch(void* const* d_in, const int* in_sizes, int n_in,
                              void* d_out, int out_size, void* d_ws, size_t ws_size,
                              hipStream_t stream) {
    const float* x = (const float*)d_in[0];
    const float* w = (const float*)d_in[1];
    const float* bias = (const float*)d_in[2];
    float* out = (float*)d_out;

    dim3 block(BLOCK, 1, 1);
    dim3 grid(W / (BLOCK * CPT), H / (STEPS * RPT), 1);
    conv3x3_stripe<<<grid, block, 0, stream>>>(x, w, bias, out);
}